// Round 1
// 1174.071 us; speedup vs baseline: 1.2247x; 1.2247x over previous
//
#include <hip/hip_runtime.h>
#include <hip/hip_bf16.h>

typedef __bf16 bf16;
typedef bf16 bf16x4 __attribute__((ext_vector_type(4)));
typedef bf16 bf16x8 __attribute__((ext_vector_type(8)));
typedef float f32x4 __attribute__((ext_vector_type(4)));

#define GLDS(g, l)                                                            \
  __builtin_amdgcn_global_load_lds(                                           \
      (const __attribute__((address_space(1))) void*)(g),                     \
      (__attribute__((address_space(3))) void*)(l), 16, 0, 0)

constexpr int DM = 3584;
constexpr int NH = 112;
constexpr int HD = 64;
constexpr int DSTATE = 64;
constexpr int CH = 256;
constexpr int NG = 2;
constexpr int SEQ = 4096;
constexpr int INNER = NH * HD;    // 7168
constexpr int NCHUNK = SEQ / CH;  // 16
constexpr int HPG = NH / NG;      // 56

__device__ __forceinline__ float softplus_f(float x) {
  return x > 15.f ? x : log1pf(expf(x));
}

__device__ __forceinline__ f32x4 mfma_bf16(bf16x8 a, bf16x8 b, f32x4 c) {
  return __builtin_amdgcn_mfma_f32_16x16x32_bf16(a, b, c, 0, 0, 0);
}

__device__ __forceinline__ void wgbar() {
  asm volatile("" ::: "memory");
  __builtin_amdgcn_s_barrier();
  asm volatile("" ::: "memory");
}

// ---------------- f32 -> bf16 convert (n multiple of 4) ----------------
__global__ __launch_bounds__(256) void k_cvt(const float* __restrict__ in,
                                             bf16* __restrict__ out, int n4) {
  int i = blockIdx.x * 256 + threadIdx.x;
  if (i >= n4) return;
  float4 v = reinterpret_cast<const float4*>(in)[i];
  bf16x4 o;
  o[0] = (bf16)v.x; o[1] = (bf16)v.y; o[2] = (bf16)v.z; o[3] = (bf16)v.w;
  reinterpret_cast<bf16x4*>(out)[i] = o;
}

// ---------------- 256x256-tile 8-phase bf16 GEMM: C[m,n]=sum_k A[m,k]B[n,k]
// 512 threads = 8 waves (2 M x 4 N), per-wave output 128x64.
// LDS 128 KiB: A/B double-buffered as two K-half tiles [256][32] each.
// Counted vmcnt(8) pipeline (never 0 in steady state), swizzled (2-way-free)
// ds_read_b128 via pre-swizzled global_load_lds sources, setprio around MFMA.
// MODE 0: store bf16 transposed out[n*SEQ + m]        (x -> xT buffer)
// MODE 1: store bf16 natural    out[m*INNER + n]      (z buffer)
// MODE 2: store f32  natural    out[m*DM + n]         (final output)
template <int MODE>
__global__ __launch_bounds__(512, 2) void k_gemm(const bf16* __restrict__ A,
                                                 const bf16* __restrict__ B,
                                                 void* __restrict__ outp, int K) {
  __shared__ alignas(16) bf16 lds[65536];  // 128 KiB
  char* ldsb = (char*)lds;

  const int t = threadIdx.x;
  const int lane = t & 63, wv = t >> 6;
  const int wm = wv >> 2, wn = wv & 3;
  const int l16 = lane & 15, quad = lane >> 4;

  // XCD-aware bijective block swizzle (all our grids have nwg % 8 == 0)
  int nwg = gridDim.x * gridDim.y;
  int orig = blockIdx.y * gridDim.x + blockIdx.x;
  int swz = (nwg & 7) ? orig : (orig & 7) * (nwg >> 3) + (orig >> 3);
  const long n0 = (long)(swz % gridDim.x) * 256;
  const long m0 = (long)(swz / gridDim.x) * 256;

  // ---- staging: per-lane pre-swizzled global sources (linear LDS dest) ----
  // LDS slot layout (one K-half tile, 16 KiB): global row g, col-byte c:
  //   addr = (g>>1)*128 + ((((g&1)<<2)+(c>>4)) ^ ((g>>1)&7))*16 + (c&15)
  const int r2 = t >> 3;               // row-pair within 128-row pass
  const int cgl = (t & 7) ^ (r2 & 7);  // linear col-group this thread feeds
  const int gsr = r2 * 2 + (cgl >> 2); // global row within pass
  const int cel = (cgl & 3) * 8;       // col element offset
  const bf16* pA0 = A + (m0 + gsr) * (size_t)K + cel;
  const bf16* pA1 = pA0 + (size_t)128 * K;
  const bf16* pB0 = B + (n0 + gsr) * (size_t)K + cel;
  const bf16* pB1 = pB0 + (size_t)128 * K;

  // ---- fragment-read lane offsets (match the swizzle; 2 lanes/bank) ----
  const int swzr = (((l16 & 1) << 2) + quad) ^ ((l16 >> 1) & 7);
  const int offA = (wm * 64 + (l16 >> 1)) * 128 + swzr * 16;
  const int offB = (wn * 32 + (l16 >> 1)) * 128 + swzr * 16;

  f32x4 acc[8][4] = {};
  bf16x8 af[4], bfr[4];
  const int NT = K >> 6;

#define STG_A(koff, slot)                        \
  GLDS(pA0 + (koff), ldsb + (slot) + t * 16);    \
  GLDS(pA1 + (koff), ldsb + (slot) + 8192 + t * 16)
#define STG_B(koff, slot)                        \
  GLDS(pB0 + (koff), ldsb + (slot) + t * 16);    \
  GLDS(pB1 + (koff), ldsb + (slot) + 8192 + t * 16)
#define LD_A(mh, slot)                                                 \
  _Pragma("unroll") for (int mf = 0; mf < 4; ++mf)                     \
      af[mf] = *reinterpret_cast<const bf16x8*>(                       \
          ldsb + (slot) + offA + ((mh) * 4 + mf) * 1024)
#define LD_B(slot)                                                     \
  _Pragma("unroll") for (int nf = 0; nf < 4; ++nf)                     \
      bfr[nf] = *reinterpret_cast<const bf16x8*>(                      \
          ldsb + (slot) + offB + nf * 1024)
#define MFMA16(mh)                                                     \
  __builtin_amdgcn_s_setprio(1);                                       \
  _Pragma("unroll") for (int mf = 0; mf < 4; ++mf)                     \
      _Pragma("unroll") for (int nf = 0; nf < 4; ++nf)                 \
          acc[(mh) * 4 + mf][nf] =                                     \
              mfma_bf16(af[mf], bfr[nf], acc[(mh) * 4 + mf][nf]);      \
  __builtin_amdgcn_s_setprio(0)
#define VMW(n) asm volatile("s_waitcnt vmcnt(" #n ")" ::: "memory")

  // slot byte bases: A(buf,kh) = (buf*2+kh)*16384; B(buf,kh) = 65536 + same.
  // prologue: stage tile0 kh0, tile0 kh1, tile1 kh0 (6 half-tiles, 12 loads)
  STG_A(0, 0);
  STG_B(0, 65536);
  STG_A(32, 16384);
  STG_B(32, 65536 + 16384);
  STG_A(64, 32768);
  STG_B(64, 65536 + 32768);
  VMW(8);  // tile0 kh0 landed; 4 half-tiles stay in flight
  wgbar();

  int buf = 0;
  for (int tt = 0; tt < NT; ++tt, buf ^= 1) {
    const int aB = buf * 32768, oB = 32768 - aB;
    const int sA0 = aB, sA1 = aB + 16384;
    const int sB0 = 65536 + aB, sB1 = 65536 + aB + 16384;
    const int oA1 = oB + 16384, oB1 = 65536 + oB + 16384;
    const int k1 = (tt + 1) * 64 + 32;  // next tile, kh1
    const int k2 = (tt + 2) * 64;       // tile+2, kh0

    // phase 0: reads kh0 (B all, A mh0); stage A[t+1]kh1
    LD_B(sB0);
    LD_A(0, sA0);
    if (tt + 1 < NT) { STG_A(k1, oA1); }
    wgbar();
    MFMA16(0);
    wgbar();
    // phase 1: reads kh0 (A mh1); stage B[t+1]kh1; drain for kh1 reads
    LD_A(1, sA0);
    if (tt + 1 < NT) { STG_B(k1, oB1); }
    wgbar();
    MFMA16(1);
    if (tt + 1 < NT) { VMW(8); } else { VMW(0); }
    wgbar();
    // phase 2: reads kh1 (B all, A mh0); stage A[t+2]kh0 (kh0 slots now dead)
    LD_B(sB1);
    LD_A(0, sA1);
    if (tt + 2 < NT) { STG_A(k2, sA0); }
    wgbar();
    MFMA16(0);
    wgbar();
    // phase 3: reads kh1 (A mh1); stage B[t+2]kh0; drain for next tile kh0
    LD_A(1, sA1);
    if (tt + 2 < NT) { STG_B(k2, sB0); }
    wgbar();
    MFMA16(1);
    if (tt + 2 < NT) { VMW(8); }
    else if (tt + 1 < NT) { VMW(4); }
    wgbar();
  }

#undef STG_A
#undef STG_B
#undef LD_A
#undef LD_B
#undef MFMA16
#undef VMW

#pragma unroll
  for (int mf = 0; mf < 8; ++mf)
#pragma unroll
    for (int nf = 0; nf < 4; ++nf) {
      long col = n0 + wn * 64 + nf * 16 + l16;
      long mg = m0 + wm * 128 + mf * 16 + quad * 4;
      if constexpr (MODE == 0) {
        bf16* o = (bf16*)outp;
        bf16x4 v;
#pragma unroll
        for (int u = 0; u < 4; u++) v[u] = (bf16)acc[mf][nf][u];
        *reinterpret_cast<bf16x4*>(&o[col * SEQ + mg]) = v;
      } else if constexpr (MODE == 1) {
        bf16* o = (bf16*)outp;
#pragma unroll
        for (int u = 0; u < 4; u++)
          o[(mg + u) * (long)INNER + col] = (bf16)acc[mf][nf][u];
      } else {
        float* o = (float*)outp;
#pragma unroll
        for (int u = 0; u < 4; u++)
          o[(mg + u) * (long)DM + col] = acc[mf][nf][u];
      }
    }
}

// ---------------- per-(chunk,head) end-state: states[p,n] -------------
// states = dts * sum_j x[j,p] * B[j,n] * exp(dAh*(255-j))
__global__ __launch_bounds__(256) void k_states(const bf16* __restrict__ xT,
                                                const bf16* __restrict__ Bbf,
                                                const float* __restrict__ A_log,
                                                const float* __restrict__ dt_bias,
                                                float* __restrict__ states) {
  const int kc = blockIdx.x;
  const int h = blockIdx.y;
  const int g = h / HPG;
  const int t = threadIdx.x;
  const int wave = t >> 6, lane = t & 63, quad = lane >> 4, l16 = lane & 15;
  const float dts = softplus_f(0.1f + dt_bias[h]);
  const float dAh = -expf(A_log[h]) * dts;

  __shared__ alignas(16) bf16 xTs[64 * 136];
  __shared__ alignas(16) bf16 BTs[64 * 136];

  const bf16* srcX = xT + (size_t)h * 64 * SEQ + (size_t)kc * CH;
  const bf16* srcB = Bbf + ((size_t)kc * CH * NG + g) * DSTATE;

  f32x4 acc[4] = {};

  for (int half = 0; half < 2; half++) {
    __syncthreads();
    // x^T tile [p][128 j], contiguous rows from xT
#pragma unroll
    for (int q = 0; q < 4; q++) {
      int u = q * 256 + t;
      int row = u >> 4, c8 = (u & 15) * 8;
      bf16x8 v = *reinterpret_cast<const bf16x8*>(&srcX[(size_t)row * SEQ + half * 128 + c8]);
      *reinterpret_cast<bf16x8*>(&xTs[row * 136 + c8]) = v;
    }
    // B^T tile [n][128 j] with decay scale folded in
#pragma unroll
    for (int q = 0; q < 4; q++) {
      int u = q * 256 + t;
      int jl = u & 127, n8 = (u >> 7) * 8;
      int j = half * 128 + jl;
      bf16x8 v = *reinterpret_cast<const bf16x8*>(&srcB[(size_t)j * (NG * DSTATE) + n8]);
      float s = expf(dAh * (float)(CH - 1 - j));
#pragma unroll
      for (int e = 0; e < 8; e++)
        BTs[(n8 + e) * 136 + jl] = (bf16)((float)v[e] * s);
    }
    __syncthreads();
#pragma unroll
    for (int kk = 0; kk < 4; kk++) {
      bf16x8 a = *reinterpret_cast<const bf16x8*>(&xTs[(wave * 16 + l16) * 136 + kk * 32 + quad * 8]);
#pragma unroll
      for (int tn = 0; tn < 4; tn++) {
        bf16x8 b = *reinterpret_cast<const bf16x8*>(&BTs[(tn * 16 + l16) * 136 + kk * 32 + quad * 8]);
        acc[tn] = mfma_bf16(a, b, acc[tn]);
      }
    }
  }
  float* dst = states + (size_t)(kc * NH + h) * 64 * 64;
#pragma unroll
  for (int tn = 0; tn < 4; tn++)
#pragma unroll
    for (int u = 0; u < 4; u++) {
      int p = wave * 16 + quad * 4 + u;
      dst[p * 64 + tn * 16 + l16] = acc[tn][u] * dts;
    }
}

// ---------------- inter-chunk scan, in place: states[k] <- entering state
__global__ __launch_bounds__(256) void k_scan(float* __restrict__ states,
                                              const float* __restrict__ A_log,
                                              const float* __restrict__ dt_bias) {
  int idx = blockIdx.x * 256 + threadIdx.x;  // NH*4096 total
  int h = idx >> 12;
  int pn = idx & 4095;
  float dts = softplus_f(0.1f + dt_bias[h]);
  float dAh = -expf(A_log[h]) * dts;
  float cd = expf(dAh * (float)CH);
  float carry = 0.f;
  float* p = states + (size_t)h * 4096 + pn;
  const size_t stride = (size_t)NH * 4096;
#pragma unroll
  for (int k = 0; k < NCHUNK; k++) {
    float s = p[k * stride];
    p[k * stride] = carry;
    carry = carry * cd + s;
  }
}

// ---------------- per-(h,chunk,half) output: Y = (S.L).x + C.prev^T + D*x, gated
__global__ __launch_bounds__(256) void k_y(const bf16* __restrict__ xT,
                                           const bf16* __restrict__ Bbf,
                                           const bf16* __restrict__ Cbf,
                                           const float* __restrict__ prev,
                                           bf16* __restrict__ zy,  // in: z, out: y
                                           const float* __restrict__ A_log,
                                           const float* __restrict__ Dvec,
                                           const float* __restrict__ dt_bias) {
  const int half = blockIdx.x;
  const int kc = blockIdx.y;
  const int h = blockIdx.z;
  const int g = h / HPG;
  const int i0 = half * 128;
  const int t = threadIdx.x;
  const int wave = t >> 6, lane = t & 63, quad = lane >> 4, l16 = lane & 15;
  const float dts = softplus_f(0.1f + dt_bias[h]);
  const float dAh = -expf(A_log[h]) * dts;
  const float Dh = Dvec[h];

  __shared__ alignas(16) bf16 Cs[128 * 72];
  __shared__ alignas(16) bf16 Bsh[64 * 72];  // B panel; also holds prev first
  __shared__ alignas(16) bf16 xTs[64 * 72];
  __shared__ alignas(16) bf16 Ws[128 * 72];

  {  // stage C rows [i0..i0+128)
    const bf16* src = Cbf + ((size_t)(kc * CH + i0) * NG + g) * DSTATE;
#pragma unroll
    for (int q = 0; q < 4; q++) {
      int u = q * 256 + t;
      int row = u >> 3, c8 = (u & 7) * 8;
      bf16x8 v = *reinterpret_cast<const bf16x8*>(&src[(size_t)row * (NG * DSTATE) + c8]);
      *reinterpret_cast<bf16x8*>(&Cs[row * 72 + c8]) = v;
    }
  }
  {  // stage prev [p][n] -> bf16 into Bsh
    const float* src = prev + (size_t)(kc * NH + h) * 4096;
#pragma unroll
    for (int q = 0; q < 4; q++) {
      int u = q * 256 + t;
      int p = u >> 4, c4 = (u & 15) * 4;
      float4 v = *reinterpret_cast<const float4*>(&src[p * 64 + c4]);
      bf16x4 o;
      o[0] = (bf16)v.x; o[1] = (bf16)v.y; o[2] = (bf16)v.z; o[3] = (bf16)v.w;
      *reinterpret_cast<bf16x4*>(&Bsh[p * 72 + c4]) = o;
    }
  }
  __syncthreads();

  f32x4 accY[2][4] = {};
  // Y_off = C . prev^T   (K = n-state)
#pragma unroll
  for (int kk = 0; kk < 2; kk++) {
    bf16x8 a0 = *reinterpret_cast<const bf16x8*>(&Cs[(wave * 32 + l16) * 72 + kk * 32 + quad * 8]);
    bf16x8 a1 = *reinterpret_cast<const bf16x8*>(&Cs[(wave * 32 + 16 + l16) * 72 + kk * 32 + quad * 8]);
#pragma unroll
    for (int tn = 0; tn < 4; tn++) {
      bf16x8 b = *reinterpret_cast<const bf16x8*>(&Bsh[(tn * 16 + l16) * 72 + kk * 32 + quad * 8]);
      accY[0][tn] = mfma_bf16(a0, b, accY[0][tn]);
      accY[1][tn] = mfma_bf16(a1, b, accY[1][tn]);
    }
  }
  // scale Y_off by exp(dAh*(i+1))
#pragma unroll
  for (int tm = 0; tm < 2; tm++)
#pragma unroll
    for (int u = 0; u < 4; u++) {
      float sc = expf(dAh * (float)(i0 + wave * 32 + tm * 16 + quad * 4 + u + 1));
#pragma unroll
      for (int tn = 0; tn < 4; tn++) accY[tm][tn][u] *= sc;
    }

  const int npan = half ? 4 : 2;  // skip all-masked panels
  for (int jb = 0; jb < npan; jb++) {
    __syncthreads();
    {  // stage B panel rows j in [jb*64, jb*64+64)
      const bf16* src = Bbf + ((size_t)(kc * CH + jb * 64) * NG + g) * DSTATE;
#pragma unroll
      for (int q = 0; q < 2; q++) {
        int u = q * 256 + t;
        int row = u >> 3, c8 = (u & 7) * 8;
        bf16x8 v = *reinterpret_cast<const bf16x8*>(&src[(size_t)row * (NG * DSTATE) + c8]);
        *reinterpret_cast<bf16x8*>(&Bsh[row * 72 + c8]) = v;
      }
    }
    {  // stage x^T panel [p][64 j]
      const bf16* src = xT + (size_t)h * 64 * SEQ + (size_t)kc * CH + jb * 64;
#pragma unroll
      for (int q = 0; q < 2; q++) {
        int u = q * 256 + t;
        int row = u >> 3, c8 = (u & 7) * 8;
        bf16x8 v = *reinterpret_cast<const bf16x8*>(&src[(size_t)row * SEQ + c8]);
        *reinterpret_cast<bf16x8*>(&xTs[row * 72 + c8]) = v;
      }
    }
    __syncthreads();
    // S = C . B^T (K = n-state)
    f32x4 accS[2][4] = {};
#pragma unroll
    for (int kk = 0; kk < 2; kk++) {
      bf16x8 a0 = *reinterpret_cast<const bf16x8*>(&Cs[(wave * 32 + l16) * 72 + kk * 32 + quad * 8]);
      bf16x8 a1 = *reinterpret_cast<const bf16x8*>(&Cs[(wave * 32 + 16 + l16) * 72 + kk * 32 + quad * 8]);
#pragma unroll
      for (int tj = 0; tj < 4; tj++) {
        bf16x8 b = *reinterpret_cast<const bf16x8*>(&Bsh[(tj * 16 + l16) * 72 + kk * 32 + quad * 8]);
        accS[0][tj] = mfma_bf16(a0, b, accS[0][tj]);
        accS[1][tj] = mfma_bf16(a1, b, accS[1][tj]);
      }
    }
    // W = S .* (dts * r^(i-j), i>=j) -> LDS (per-wave-private rows)
#pragma unroll
    for (int tm = 0; tm < 2; tm++)
#pragma unroll
      for (int tj = 0; tj < 4; tj++)
#pragma unroll
        for (int u = 0; u < 4; u++) {
          int li = wave * 32 + tm * 16 + quad * 4 + u;
          int ai = i0 + li;
          int aj = jb * 64 + tj * 16 + l16;
          float s = (ai >= aj) ? dts * expf(dAh * (float)(ai - aj)) : 0.f;
          Ws[li * 72 + tj * 16 + l16] = (bf16)(accS[tm][tj][u] * s);
        }
    // Y += W . x   (K = j)
#pragma unroll
    for (int kk = 0; kk < 2; kk++) {
      bf16x8 a0 = *reinterpret_cast<const bf16x8*>(&Ws[(wave * 32 + l16) * 72 + kk * 32 + quad * 8]);
      bf16x8 a1 = *reinterpret_cast<const bf16x8*>(&Ws[(wave * 32 + 16 + l16) * 72 + kk * 32 + quad * 8]);
#pragma unroll
      for (int tn = 0; tn < 4; tn++) {
        bf16x8 b = *reinterpret_cast<const bf16x8*>(&xTs[(tn * 16 + l16) * 72 + kk * 32 + quad * 8]);
        accY[0][tn] = mfma_bf16(a0, b, accY[0][tn]);
        accY[1][tn] = mfma_bf16(a1, b, accY[1][tn]);
      }
    }
  }

  // epilogue: + D*x, gate with sigmoid(z), write y in place over z
#pragma unroll
  for (int tm = 0; tm < 2; tm++)
#pragma unroll
    for (int tn = 0; tn < 4; tn++)
#pragma unroll
      for (int u = 0; u < 4; u++) {
        int li = wave * 32 + tm * 16 + quad * 4 + u;
        long lg = (long)kc * CH + i0 + li;
        int p = tn * 16 + l16;
        float xv = (float)xT[(size_t)(h * 64 + p) * SEQ + lg];
        float yv = accY[tm][tn][u] + xv * Dh;
        size_t off = (size_t)lg * INNER + h * 64 + p;
        float zv = (float)zy[off];
        float gate = 1.f / (1.f + expf(-zv));
        zy[off] = (bf16)(yv * gate);
      }
}

extern "C" void kernel_launch(void* const* d_in, const int* in_sizes, int n_in,
                              void* d_out, int out_size, void* d_ws, size_t ws_size,
                              hipStream_t stream) {
  const float* hs    = (const float*)d_in[0];
  const float* W_in  = (const float*)d_in[1];
  const float* W_out = (const float*)d_in[2];
  const float* A_log = (const float*)d_in[3];
  const float* Dv    = (const float*)d_in[4];
  const float* dtb   = (const float*)d_in[5];
  const float* Bin   = (const float*)d_in[6];
  const float* Cin   = (const float*)d_in[7];

  char* ws = (char*)d_ws;
  size_t off = 0;
  auto alloc = [&](size_t bytes) {
    void* p = ws + off;
    off += (bytes + 255) & ~(size_t)255;
    return p;
  };
  bf16* wbuf = (bf16*)alloc((size_t)INNER * DM * 2);        // reused: Win half0, half1, Wout
  bf16* hsb  = (bf16*)alloc((size_t)SEQ * DM * 2);
  bf16* xTg  = (bf16*)alloc((size_t)INNER * SEQ * 2);       // x transposed [h*p][L]
  bf16* zy   = (bf16*)alloc((size_t)SEQ * INNER * 2);       // z, overwritten by y
  bf16* Bbf  = (bf16*)alloc((size_t)SEQ * NG * DSTATE * 2);
  bf16* Cbf  = (bf16*)alloc((size_t)SEQ * NG * DSTATE * 2);
  float* st  = (float*)alloc((size_t)NCHUNK * NH * 64 * 64 * 4);

  auto cvt = [&](const float* src, bf16* dst, size_t n) {
    int n4 = (int)(n / 4);
    k_cvt<<<dim3((n4 + 255) / 256), dim3(256), 0, stream>>>(src, dst, n4);
  };

  cvt(hs, hsb, (size_t)SEQ * DM);
  cvt(Bin, Bbf, (size_t)SEQ * NG * DSTATE);
  cvt(Cin, Cbf, (size_t)SEQ * NG * DSTATE);

  dim3 blk(256);
  dim3 gblk(512);
  dim3 g1(INNER / 256, SEQ / 256);  // 28 x 16 = 448 blocks
  dim3 g2(DM / 256, SEQ / 256);     // 14 x 16 = 224 blocks

  // GEMM1 half 0 (x) -> transposed store
  cvt(W_in, wbuf, (size_t)INNER * DM);
  k_gemm<0><<<g1, gblk, 0, stream>>>(hsb, wbuf, xTg, DM);
  // GEMM1 half 1 (z) -> natural store
  cvt(W_in + (size_t)INNER * DM, wbuf, (size_t)INNER * DM);
  k_gemm<1><<<g1, gblk, 0, stream>>>(hsb, wbuf, zy, DM);
  // W_out conversion (wbuf free after GEMM1)
  cvt(W_out, wbuf, (size_t)DM * INNER);

  k_states<<<dim3(NCHUNK, NH), blk, 0, stream>>>(xTg, Bbf, A_log, dtb, st);
  k_scan<<<dim3((NH * 4096) / 256), blk, 0, stream>>>(st, A_log, dtb);
  k_y<<<dim3(2, NCHUNK, NH), blk, 0, stream>>>(xTg, Bbf, Cbf, st, zy, A_log, Dv, dtb);

  k_gemm<2><<<g2, gblk, 0, stream>>>(zy, wbuf, d_out, INNER);

  (void)in_sizes; (void)n_in; (void)out_size; (void)ws_size;
}

// Round 2
// 1161.810 us; speedup vs baseline: 1.2376x; 1.0106x over previous
//
#include <hip/hip_runtime.h>
#include <hip/hip_bf16.h>

typedef __bf16 bf16;
typedef bf16 bf16x4 __attribute__((ext_vector_type(4)));
typedef bf16 bf16x8 __attribute__((ext_vector_type(8)));
typedef float f32x4 __attribute__((ext_vector_type(4)));

#define GLDS(g, l)                                                            \
  __builtin_amdgcn_global_load_lds(                                           \
      (const __attribute__((address_space(1))) void*)(g),                     \
      (__attribute__((address_space(3))) void*)(l), 16, 0, 0)

constexpr int DM = 3584;
constexpr int NH = 112;
constexpr int HD = 64;
constexpr int DSTATE = 64;
constexpr int CH = 256;
constexpr int NG = 2;
constexpr int SEQ = 4096;
constexpr int INNER = NH * HD;    // 7168
constexpr int NCHUNK = SEQ / CH;  // 16
constexpr int HPG = NH / NG;      // 56

__device__ __forceinline__ float softplus_f(float x) {
  return x > 15.f ? x : log1pf(expf(x));
}

__device__ __forceinline__ f32x4 mfma_bf16(bf16x8 a, bf16x8 b, f32x4 c) {
  return __builtin_amdgcn_mfma_f32_16x16x32_bf16(a, b, c, 0, 0, 0);
}

__device__ __forceinline__ void wgbar() {
  asm volatile("" ::: "memory");
  __builtin_amdgcn_s_barrier();
  asm volatile("" ::: "memory");
}

// ---------------- f32 -> bf16 convert (n multiple of 4) ----------------
__global__ __launch_bounds__(256) void k_cvt(const float* __restrict__ in,
                                             bf16* __restrict__ out, int n4) {
  int i = blockIdx.x * 256 + threadIdx.x;
  if (i >= n4) return;
  float4 v = reinterpret_cast<const float4*>(in)[i];
  bf16x4 o;
  o[0] = (bf16)v.x; o[1] = (bf16)v.y; o[2] = (bf16)v.z; o[3] = (bf16)v.w;
  reinterpret_cast<bf16x4*>(out)[i] = o;
}

// ---------------- 256x256-tile 8-phase bf16 GEMM: C[m,n]=sum_k A[m,k]B[n,k]
// 512 threads = 8 waves (2 M x 4 N), per-wave output 128x64.
// LDS 128 KiB: A/B double-buffered as two K-half tiles [256][32] each.
// Counted vmcnt(8) pipeline, swizzled conflict-free ds_read_b128 via
// pre-swizzled global_load_lds sources, setprio around MFMA.
// 2D XCD region swizzle: XCD = 2 n-cols x 4 m-rows; m-fastest traversal so
// the 32 concurrent blocks per XCD share 4 A-strips + 8 B-panels (L2-hot
// K-slice ~1.5 MB) and K-synchronized staging hits L2/L3 instead of HBM.
// MODE 0: store bf16 transposed out[n*SEQ + m]        (x -> xT buffer)
// MODE 1: store bf16 natural    out[m*INNER + n]      (z buffer)
// MODE 2: store f32  natural    out[m*DM + n]         (final output)
template <int MODE>
__global__ __launch_bounds__(512, 2) void k_gemm(const bf16* __restrict__ A,
                                                 const bf16* __restrict__ B,
                                                 void* __restrict__ outp, int K) {
  __shared__ alignas(16) bf16 lds[65536];  // 128 KiB
  char* ldsb = (char*)lds;

  const int t = threadIdx.x;
  const int lane = t & 63, wv = t >> 6;
  const int wm = wv >> 2, wn = wv & 3;
  const int l16 = lane & 15, quad = lane >> 4;

  // 2D XCD-region block swizzle (bijective when gx%2==0 && gy%4==0)
  const int gx = gridDim.x, gy = gridDim.y;
  const int orig = blockIdx.y * gx + blockIdx.x;
  long m0, n0;
  if ((gx % 2) == 0 && (gy % 4) == 0) {
    const int xcd = orig & 7;       // HW round-robin XCD assignment
    const int l = orig >> 3;        // local index within XCD's region
    const int xc = xcd & 1, xr = xcd >> 1;
    const int RN = gx >> 1, RM = gy >> 2;
    const int lm = l & (RM - 1);    // RM is 4 for our grids
    const int ln = l >> 2;
    m0 = (long)(xr * RM + lm) * 256;
    n0 = (long)(xc * RN + ln) * 256;
  } else {
    n0 = (long)blockIdx.x * 256;
    m0 = (long)blockIdx.y * 256;
  }

  // ---- staging: per-lane pre-swizzled global sources (linear LDS dest) ----
  // LDS slot layout (one K-half tile, 16 KiB): global row g, col-byte c:
  //   addr = (g>>1)*128 + ((((g&1)<<2)+(c>>4)) ^ ((g>>1)&7))*16 + (c&15)
  const int r2 = t >> 3;               // row-pair within 128-row pass
  const int cgl = (t & 7) ^ (r2 & 7);  // linear col-group this thread feeds
  const int gsr = r2 * 2 + (cgl >> 2); // global row within pass
  const int cel = (cgl & 3) * 8;       // col element offset
  const bf16* pA0 = A + (m0 + gsr) * (size_t)K + cel;
  const bf16* pA1 = pA0 + (size_t)128 * K;
  const bf16* pB0 = B + (n0 + gsr) * (size_t)K + cel;
  const bf16* pB1 = pB0 + (size_t)128 * K;

  // ---- fragment-read lane offsets (match the swizzle; 2 lanes/bank) ----
  const int swzr = (((l16 & 1) << 2) + quad) ^ ((l16 >> 1) & 7);
  const int offA = (wm * 64 + (l16 >> 1)) * 128 + swzr * 16;
  const int offB = (wn * 32 + (l16 >> 1)) * 128 + swzr * 16;

  f32x4 acc[8][4] = {};
  bf16x8 af[4], bfr[4];
  const int NT = K >> 6;

#define STG_A(koff, slot)                        \
  GLDS(pA0 + (koff), ldsb + (slot) + t * 16);    \
  GLDS(pA1 + (koff), ldsb + (slot) + 8192 + t * 16)
#define STG_B(koff, slot)                        \
  GLDS(pB0 + (koff), ldsb + (slot) + t * 16);    \
  GLDS(pB1 + (koff), ldsb + (slot) + 8192 + t * 16)
#define LD_A(mh, slot)                                                 \
  _Pragma("unroll") for (int mf = 0; mf < 4; ++mf)                     \
      af[mf] = *reinterpret_cast<const bf16x8*>(                       \
          ldsb + (slot) + offA + ((mh) * 4 + mf) * 1024)
#define LD_B(slot)                                                     \
  _Pragma("unroll") for (int nf = 0; nf < 4; ++nf)                     \
      bfr[nf] = *reinterpret_cast<const bf16x8*>(                      \
          ldsb + (slot) + offB + nf * 1024)
#define MFMA16(mh)                                                     \
  __builtin_amdgcn_s_setprio(1);                                       \
  _Pragma("unroll") for (int mf = 0; mf < 4; ++mf)                     \
      _Pragma("unroll") for (int nf = 0; nf < 4; ++nf)                 \
          acc[(mh) * 4 + mf][nf] =                                     \
              mfma_bf16(af[mf], bfr[nf], acc[(mh) * 4 + mf][nf]);      \
  __builtin_amdgcn_s_setprio(0)
#define VMW(n) asm volatile("s_waitcnt vmcnt(" #n ")" ::: "memory")

  // slot byte bases: A(buf,kh) = (buf*2+kh)*16384; B(buf,kh) = 65536 + same.
  // prologue: stage tile0 kh0, tile0 kh1, tile1 kh0 (6 half-tiles, 12 loads)
  STG_A(0, 0);
  STG_B(0, 65536);
  STG_A(32, 16384);
  STG_B(32, 65536 + 16384);
  STG_A(64, 32768);
  STG_B(64, 65536 + 32768);
  VMW(8);  // tile0 kh0 landed; 4 half-tiles stay in flight
  wgbar();

  int buf = 0;
  for (int tt = 0; tt < NT; ++tt, buf ^= 1) {
    const int aB = buf * 32768, oB = 32768 - aB;
    const int sA0 = aB, sA1 = aB + 16384;
    const int sB0 = 65536 + aB, sB1 = 65536 + aB + 16384;
    const int oA1 = oB + 16384, oB1 = 65536 + oB + 16384;
    const int k1 = (tt + 1) * 64 + 32;  // next tile, kh1
    const int k2 = (tt + 2) * 64;       // tile+2, kh0

    // phase 0: stage A[t+1]kh1 first, then read kh0 (B all, A mh0)
    if (tt + 1 < NT) { STG_A(k1, oA1); }
    LD_B(sB0);
    LD_A(0, sA0);
    wgbar();
    MFMA16(0);
    wgbar();
    // phase 1: stage B[t+1]kh1; read kh0 (A mh1); drain for kh1 reads
    if (tt + 1 < NT) { STG_B(k1, oB1); }
    LD_A(1, sA0);
    wgbar();
    MFMA16(1);
    if (tt + 1 < NT) { VMW(8); } else { VMW(0); }
    wgbar();
    // phase 2: stage A[t+2]kh0 (kh0 slots now dead); read kh1 (B all, A mh0)
    if (tt + 2 < NT) { STG_A(k2, sA0); }
    LD_B(sB1);
    LD_A(0, sA1);
    wgbar();
    MFMA16(0);
    wgbar();
    // phase 3: stage B[t+2]kh0; read kh1 (A mh1); drain for next tile kh0
    if (tt + 2 < NT) { STG_B(k2, sB0); }
    LD_A(1, sA1);
    wgbar();
    MFMA16(1);
    if (tt + 2 < NT) { VMW(8); }
    else if (tt + 1 < NT) { VMW(4); }
    wgbar();
  }

#undef STG_A
#undef STG_B
#undef LD_A
#undef LD_B
#undef MFMA16
#undef VMW

#pragma unroll
  for (int mf = 0; mf < 8; ++mf)
#pragma unroll
    for (int nf = 0; nf < 4; ++nf) {
      long col = n0 + wn * 64 + nf * 16 + l16;
      long mg = m0 + wm * 128 + mf * 16 + quad * 4;
      if constexpr (MODE == 0) {
        bf16* o = (bf16*)outp;
        bf16x4 v;
#pragma unroll
        for (int u = 0; u < 4; u++) v[u] = (bf16)acc[mf][nf][u];
        *reinterpret_cast<bf16x4*>(&o[col * SEQ + mg]) = v;
      } else if constexpr (MODE == 1) {
        bf16* o = (bf16*)outp;
#pragma unroll
        for (int u = 0; u < 4; u++)
          o[(mg + u) * (long)INNER + col] = (bf16)acc[mf][nf][u];
      } else {
        float* o = (float*)outp;
#pragma unroll
        for (int u = 0; u < 4; u++)
          o[(mg + u) * (long)DM + col] = acc[mf][nf][u];
      }
    }
}

// ---------------- per-(chunk,head) end-state: states[p,n] -------------
// states = dts * sum_j x[j,p] * B[j,n] * exp(dAh*(255-j))
__global__ __launch_bounds__(256) void k_states(const bf16* __restrict__ xT,
                                                const bf16* __restrict__ Bbf,
                                                const float* __restrict__ A_log,
                                                const float* __restrict__ dt_bias,
                                                float* __restrict__ states) {
  const int kc = blockIdx.x;
  const int h = blockIdx.y;
  const int g = h / HPG;
  const int t = threadIdx.x;
  const int wave = t >> 6, lane = t & 63, quad = lane >> 4, l16 = lane & 15;
  const float dts = softplus_f(0.1f + dt_bias[h]);
  const float dAh = -expf(A_log[h]) * dts;

  __shared__ alignas(16) bf16 xTs[64 * 136];
  __shared__ alignas(16) bf16 BTs[64 * 136];

  const bf16* srcX = xT + (size_t)h * 64 * SEQ + (size_t)kc * CH;
  const bf16* srcB = Bbf + ((size_t)kc * CH * NG + g) * DSTATE;

  f32x4 acc[4] = {};

  for (int half = 0; half < 2; half++) {
    __syncthreads();
    // x^T tile [p][128 j], contiguous rows from xT
#pragma unroll
    for (int q = 0; q < 4; q++) {
      int u = q * 256 + t;
      int row = u >> 4, c8 = (u & 15) * 8;
      bf16x8 v = *reinterpret_cast<const bf16x8*>(&srcX[(size_t)row * SEQ + half * 128 + c8]);
      *reinterpret_cast<bf16x8*>(&xTs[row * 136 + c8]) = v;
    }
    // B^T tile [n][128 j] with decay scale folded in
#pragma unroll
    for (int q = 0; q < 4; q++) {
      int u = q * 256 + t;
      int jl = u & 127, n8 = (u >> 7) * 8;
      int j = half * 128 + jl;
      bf16x8 v = *reinterpret_cast<const bf16x8*>(&srcB[(size_t)j * (NG * DSTATE) + n8]);
      float s = expf(dAh * (float)(CH - 1 - j));
#pragma unroll
      for (int e = 0; e < 8; e++)
        BTs[(n8 + e) * 136 + jl] = (bf16)((float)v[e] * s);
    }
    __syncthreads();
#pragma unroll
    for (int kk = 0; kk < 4; kk++) {
      bf16x8 a = *reinterpret_cast<const bf16x8*>(&xTs[(wave * 16 + l16) * 136 + kk * 32 + quad * 8]);
#pragma unroll
      for (int tn = 0; tn < 4; tn++) {
        bf16x8 b = *reinterpret_cast<const bf16x8*>(&BTs[(tn * 16 + l16) * 136 + kk * 32 + quad * 8]);
        acc[tn] = mfma_bf16(a, b, acc[tn]);
      }
    }
  }
  float* dst = states + (size_t)(kc * NH + h) * 64 * 64;
#pragma unroll
  for (int tn = 0; tn < 4; tn++)
#pragma unroll
    for (int u = 0; u < 4; u++) {
      int p = wave * 16 + quad * 4 + u;
      dst[p * 64 + tn * 16 + l16] = acc[tn][u] * dts;
    }
}

// ---------------- inter-chunk scan, in place: states[k] <- entering state
__global__ __launch_bounds__(256) void k_scan(float* __restrict__ states,
                                              const float* __restrict__ A_log,
                                              const float* __restrict__ dt_bias) {
  int idx = blockIdx.x * 256 + threadIdx.x;  // NH*4096 total
  int h = idx >> 12;
  int pn = idx & 4095;
  float dts = softplus_f(0.1f + dt_bias[h]);
  float dAh = -expf(A_log[h]) * dts;
  float cd = expf(dAh * (float)CH);
  float carry = 0.f;
  float* p = states + (size_t)h * 4096 + pn;
  const size_t stride = (size_t)NH * 4096;
#pragma unroll
  for (int k = 0; k < NCHUNK; k++) {
    float s = p[k * stride];
    p[k * stride] = carry;
    carry = carry * cd + s;
  }
}

// ---------------- per-(h,chunk,half) output: Y = (S.L).x + C.prev^T + D*x, gated
__global__ __launch_bounds__(256) void k_y(const bf16* __restrict__ xT,
                                           const bf16* __restrict__ Bbf,
                                           const bf16* __restrict__ Cbf,
                                           const float* __restrict__ prev,
                                           bf16* __restrict__ zy,  // in: z, out: y
                                           const float* __restrict__ A_log,
                                           const float* __restrict__ Dvec,
                                           const float* __restrict__ dt_bias) {
  const int half = blockIdx.x;
  const int kc = blockIdx.y;
  const int h = blockIdx.z;
  const int g = h / HPG;
  const int i0 = half * 128;
  const int t = threadIdx.x;
  const int wave = t >> 6, lane = t & 63, quad = lane >> 4, l16 = lane & 15;
  const float dts = softplus_f(0.1f + dt_bias[h]);
  const float dAh = -expf(A_log[h]) * dts;
  const float Dh = Dvec[h];

  __shared__ alignas(16) bf16 Cs[128 * 72];
  __shared__ alignas(16) bf16 Bsh[64 * 72];  // B panel; also holds prev first
  __shared__ alignas(16) bf16 xTs[64 * 72];
  __shared__ alignas(16) bf16 Ws[128 * 72];

  {  // stage C rows [i0..i0+128)
    const bf16* src = Cbf + ((size_t)(kc * CH + i0) * NG + g) * DSTATE;
#pragma unroll
    for (int q = 0; q < 4; q++) {
      int u = q * 256 + t;
      int row = u >> 3, c8 = (u & 7) * 8;
      bf16x8 v = *reinterpret_cast<const bf16x8*>(&src[(size_t)row * (NG * DSTATE) + c8]);
      *reinterpret_cast<bf16x8*>(&Cs[row * 72 + c8]) = v;
    }
  }
  {  // stage prev [p][n] -> bf16 into Bsh
    const float* src = prev + (size_t)(kc * NH + h) * 4096;
#pragma unroll
    for (int q = 0; q < 4; q++) {
      int u = q * 256 + t;
      int p = u >> 4, c4 = (u & 15) * 4;
      float4 v = *reinterpret_cast<const float4*>(&src[p * 64 + c4]);
      bf16x4 o;
      o[0] = (bf16)v.x; o[1] = (bf16)v.y; o[2] = (bf16)v.z; o[3] = (bf16)v.w;
      *reinterpret_cast<bf16x4*>(&Bsh[p * 72 + c4]) = o;
    }
  }
  __syncthreads();

  f32x4 accY[2][4] = {};
  // Y_off = C . prev^T   (K = n-state)
#pragma unroll
  for (int kk = 0; kk < 2; kk++) {
    bf16x8 a0 = *reinterpret_cast<const bf16x8*>(&Cs[(wave * 32 + l16) * 72 + kk * 32 + quad * 8]);
    bf16x8 a1 = *reinterpret_cast<const bf16x8*>(&Cs[(wave * 32 + 16 + l16) * 72 + kk * 32 + quad * 8]);
#pragma unroll
    for (int tn = 0; tn < 4; tn++) {
      bf16x8 b = *reinterpret_cast<const bf16x8*>(&Bsh[(tn * 16 + l16) * 72 + kk * 32 + quad * 8]);
      accY[0][tn] = mfma_bf16(a0, b, accY[0][tn]);
      accY[1][tn] = mfma_bf16(a1, b, accY[1][tn]);
    }
  }
  // scale Y_off by exp(dAh*(i+1))
#pragma unroll
  for (int tm = 0; tm < 2; tm++)
#pragma unroll
    for (int u = 0; u < 4; u++) {
      float sc = expf(dAh * (float)(i0 + wave * 32 + tm * 16 + quad * 4 + u + 1));
#pragma unroll
      for (int tn = 0; tn < 4; tn++) accY[tm][tn][u] *= sc;
    }

  const int npan = half ? 4 : 2;  // skip all-masked panels
  for (int jb = 0; jb < npan; jb++) {
    __syncthreads();
    {  // stage B panel rows j in [jb*64, jb*64+64)
      const bf16* src = Bbf + ((size_t)(kc * CH + jb * 64) * NG + g) * DSTATE;
#pragma unroll
      for (int q = 0; q < 2; q++) {
        int u = q * 256 + t;
        int row = u >> 3, c8 = (u & 7) * 8;
        bf16x8 v = *reinterpret_cast<const bf16x8*>(&src[(size_t)row * (NG * DSTATE) + c8]);
        *reinterpret_cast<bf16x8*>(&Bsh[row * 72 + c8]) = v;
      }
    }
    {  // stage x^T panel [p][64 j]
      const bf16* src = xT + (size_t)h * 64 * SEQ + (size_t)kc * CH + jb * 64;
#pragma unroll
      for (int q = 0; q < 2; q++) {
        int u = q * 256 + t;
        int row = u >> 3, c8 = (u & 7) * 8;
        bf16x8 v = *reinterpret_cast<const bf16x8*>(&src[(size_t)row * SEQ + c8]);
        *reinterpret_cast<bf16x8*>(&xTs[row * 72 + c8]) = v;
      }
    }
    __syncthreads();
    // S = C . B^T (K = n-state)
    f32x4 accS[2][4] = {};
#pragma unroll
    for (int kk = 0; kk < 2; kk++) {
      bf16x8 a0 = *reinterpret_cast<const bf16x8*>(&Cs[(wave * 32 + l16) * 72 + kk * 32 + quad * 8]);
      bf16x8 a1 = *reinterpret_cast<const bf16x8*>(&Cs[(wave * 32 + 16 + l16) * 72 + kk * 32 + quad * 8]);
#pragma unroll
      for (int tj = 0; tj < 4; tj++) {
        bf16x8 b = *reinterpret_cast<const bf16x8*>(&Bsh[(tj * 16 + l16) * 72 + kk * 32 + quad * 8]);
        accS[0][tj] = mfma_bf16(a0, b, accS[0][tj]);
        accS[1][tj] = mfma_bf16(a1, b, accS[1][tj]);
      }
    }
    // W = S .* (dts * r^(i-j), i>=j) -> LDS (per-wave-private rows)
#pragma unroll
    for (int tm = 0; tm < 2; tm++)
#pragma unroll
      for (int tj = 0; tj < 4; tj++)
#pragma unroll
        for (int u = 0; u < 4; u++) {
          int li = wave * 32 + tm * 16 + quad * 4 + u;
          int ai = i0 + li;
          int aj = jb * 64 + tj * 16 + l16;
          float s = (ai >= aj) ? dts * expf(dAh * (float)(ai - aj)) : 0.f;
          Ws[li * 72 + tj * 16 + l16] = (bf16)(accS[tm][tj][u] * s);
        }
    // Y += W . x   (K = j)
#pragma unroll
    for (int kk = 0; kk < 2; kk++) {
      bf16x8 a0 = *reinterpret_cast<const bf16x8*>(&Ws[(wave * 32 + l16) * 72 + kk * 32 + quad * 8]);
      bf16x8 a1 = *reinterpret_cast<const bf16x8*>(&Ws[(wave * 32 + 16 + l16) * 72 + kk * 32 + quad * 8]);
#pragma unroll
      for (int tn = 0; tn < 4; tn++) {
        bf16x8 b = *reinterpret_cast<const bf16x8*>(&xTs[(tn * 16 + l16) * 72 + kk * 32 + quad * 8]);
        accY[0][tn] = mfma_bf16(a0, b, accY[0][tn]);
        accY[1][tn] = mfma_bf16(a1, b, accY[1][tn]);
      }
    }
  }

  // epilogue: + D*x, gate with sigmoid(z), write y in place over z
#pragma unroll
  for (int tm = 0; tm < 2; tm++)
#pragma unroll
    for (int tn = 0; tn < 4; tn++)
#pragma unroll
      for (int u = 0; u < 4; u++) {
        int li = wave * 32 + tm * 16 + quad * 4 + u;
        long lg = (long)kc * CH + i0 + li;
        int p = tn * 16 + l16;
        float xv = (float)xT[(size_t)(h * 64 + p) * SEQ + lg];
        float yv = accY[tm][tn][u] + xv * Dh;
        size_t off = (size_t)lg * INNER + h * 64 + p;
        float zv = (float)zy[off];
        float gate = 1.f / (1.f + expf(-zv));
        zy[off] = (bf16)(yv * gate);
      }
}

extern "C" void kernel_launch(void* const* d_in, const int* in_sizes, int n_in,
                              void* d_out, int out_size, void* d_ws, size_t ws_size,
                              hipStream_t stream) {
  const float* hs    = (const float*)d_in[0];
  const float* W_in  = (const float*)d_in[1];
  const float* W_out = (const float*)d_in[2];
  const float* A_log = (const float*)d_in[3];
  const float* Dv    = (const float*)d_in[4];
  const float* dtb   = (const float*)d_in[5];
  const float* Bin   = (const float*)d_in[6];
  const float* Cin   = (const float*)d_in[7];

  char* ws = (char*)d_ws;
  size_t off = 0;
  auto alloc = [&](size_t bytes) {
    void* p = ws + off;
    off += (bytes + 255) & ~(size_t)255;
    return p;
  };
  bf16* wbuf = (bf16*)alloc((size_t)INNER * DM * 2);        // reused: Win half0, half1, Wout
  bf16* hsb  = (bf16*)alloc((size_t)SEQ * DM * 2);
  bf16* xTg  = (bf16*)alloc((size_t)INNER * SEQ * 2);       // x transposed [h*p][L]
  bf16* zy   = (bf16*)alloc((size_t)SEQ * INNER * 2);       // z, overwritten by y
  bf16* Bbf  = (bf16*)alloc((size_t)SEQ * NG * DSTATE * 2);
  bf16* Cbf  = (bf16*)alloc((size_t)SEQ * NG * DSTATE * 2);
  float* st  = (float*)alloc((size_t)NCHUNK * NH * 64 * 64 * 4);

  auto cvt = [&](const float* src, bf16* dst, size_t n) {
    int n4 = (int)(n / 4);
    k_cvt<<<dim3((n4 + 255) / 256), dim3(256), 0, stream>>>(src, dst, n4);
  };

  cvt(hs, hsb, (size_t)SEQ * DM);
  cvt(Bin, Bbf, (size_t)SEQ * NG * DSTATE);
  cvt(Cin, Cbf, (size_t)SEQ * NG * DSTATE);

  dim3 blk(256);
  dim3 gblk(512);
  dim3 g1(INNER / 256, SEQ / 256);  // 28 x 16 = 448 blocks
  dim3 g2(DM / 256, SEQ / 256);     // 14 x 16 = 224 blocks

  // GEMM1 half 0 (x) -> transposed store
  cvt(W_in, wbuf, (size_t)INNER * DM);
  k_gemm<0><<<g1, gblk, 0, stream>>>(hsb, wbuf, xTg, DM);
  // GEMM1 half 1 (z) -> natural store
  cvt(W_in + (size_t)INNER * DM, wbuf, (size_t)INNER * DM);
  k_gemm<1><<<g1, gblk, 0, stream>>>(hsb, wbuf, zy, DM);
  // W_out conversion (wbuf free after GEMM1)
  cvt(W_out, wbuf, (size_t)DM * INNER);

  k_states<<<dim3(NCHUNK, NH), blk, 0, stream>>>(xTg, Bbf, A_log, dtb, st);
  k_scan<<<dim3((NH * 4096) / 256), blk, 0, stream>>>(st, A_log, dtb);
  k_y<<<dim3(2, NCHUNK, NH), blk, 0, stream>>>(xTg, Bbf, Cbf, st, zy, A_log, Dv, dtb);

  k_gemm<2><<<g2, gblk, 0, stream>>>(zy, wbuf, d_out, INNER);

  (void)in_sizes; (void)n_in; (void)out_size; (void)ws_size;
}